// Round 7
// baseline (962.267 us; speedup 1.0000x reference)
//
#include <hip/hip_runtime.h>
#include <hip/hip_bf16.h>

// GraphSAGE 2-layer forward. N=100000, E=1250000, 64 -> 64 -> 32, fp32.
//
// Round-7: fused bucket aggregation. p1 buckets edges by dst>>8 (256-node
// buckets). Then ONE block per bucket streams its edge region and pushes
// gathered rows into a 256x66 (padded) LDS f32 accumulator with ds_add_f32,
// applying mean+self+bias+ReLU in the epilogue. No CSR, no row_start, no
// bucket scan, no separate degree pass. Gather traffic (the 3.3 TB/s floor)
// unchanged; all sort/scan overhead deleted.
//
//   p1         : region[r] += (src<<8 | dst&255) for dst>>8 == r
//   dense1     : bufA = x@Ws1+b1 (f32), t1n = bf16(x@Wn1)   (MFMA split-bf16)
//   agg64_bkt  : bufA = relu(bufA + mean t1n[src]) ; inv_deg[n] = 1/max(deg,1)
//   dense2     : s2 = h1@Ws2+b2 (f32), t2n = bf16(h1@Wn2)
//   agg32_bkt  : out = s2 + mean t2n[src]

#define NF 64
#define BW2 256            // bucket width (nodes); rel = dst & 255
#define BSH 8
#define MAXB 512           // max buckets (LDS arrays in p1)
#define CAP 6144           // region capacity (mean 3197, +52 sigma)
#define P1_CHUNK 4096

typedef __attribute__((ext_vector_type(8))) short short8;
typedef __attribute__((ext_vector_type(8))) unsigned short ushort8v;
typedef __attribute__((ext_vector_type(4))) float floatx4;

__device__ __forceinline__ short bf16hi(float v) {
    __hip_bfloat16 h = __float2bfloat16(v);
    return *(short*)&h;
}
__device__ __forceinline__ float bf2f(short s) {
    __hip_bfloat16 h = *(__hip_bfloat16*)&s;
    return __bfloat162float(h);
}
__device__ __forceinline__ float bits2f(unsigned short u) {
    unsigned int x = ((unsigned int)u) << 16;
    union { unsigned int i; float f; } c; c.i = x; return c.f;
}

// ---------------- p1: bucket the edge list ----------------

__global__ __launch_bounds__(256) void p1_bucket_kernel(const int* __restrict__ src,
                                                        const int* __restrict__ dst,
                                                        int* __restrict__ gcursor,
                                                        unsigned* __restrict__ region,
                                                        int E, int nb2) {
    __shared__ int cnt[MAXB];
    __shared__ int cbase[MAXB];
    const int beg = blockIdx.x * P1_CHUNK;
    const int end = min(E, beg + P1_CHUNK);
    for (int i = threadIdx.x; i < nb2; i += 256) cnt[i] = 0;
    __syncthreads();
    for (int e = beg + threadIdx.x; e < end; e += 256)
        atomicAdd(&cnt[dst[e] >> BSH], 1);
    __syncthreads();
    for (int i = threadIdx.x; i < nb2; i += 256) {
        int c = cnt[i];
        cbase[i] = c ? atomicAdd(&gcursor[i], c) : 0;
        cnt[i] = 0;                              // reuse as local cursor
    }
    __syncthreads();
    for (int e = beg + threadIdx.x; e < end; e += 256) {
        int d = dst[e];
        int r = d >> BSH;
        int p = cbase[r] + atomicAdd(&cnt[r], 1);
        if (p < CAP)                             // clamp: no OOB even if skewed
            region[(size_t)r * CAP + p] = ((unsigned)src[e] << BSH) | (unsigned)(d & (BW2 - 1));
    }
}

// ---------------- weight prep: transpose + split-bf16, [n][72] ----------------

__global__ __launch_bounds__(256) void wprep_kernel(const float* __restrict__ Ws1,
                                                    const float* __restrict__ Wn1,
                                                    const float* __restrict__ Ws2,
                                                    const float* __restrict__ Wn2,
                                                    unsigned short* __restrict__ wt1h,
                                                    unsigned short* __restrict__ wt1l,
                                                    unsigned short* __restrict__ wt2h,
                                                    unsigned short* __restrict__ wt2l) {
    int i = blockIdx.x * 256 + threadIdx.x;
    if (i < 128 * 64) {
        int n = i >> 6, k = i & 63;
        float v = (n < 64) ? Ws1[k * 64 + n] : Wn1[k * 64 + (n - 64)];
        short hi = bf16hi(v);
        wt1h[n * 72 + k] = (unsigned short)hi;
        wt1l[n * 72 + k] = (unsigned short)bf16hi(v - bf2f(hi));
    } else if (i < 128 * 64 + 64 * 64) {
        int j = i - 128 * 64;
        int n = j >> 6, k = j & 63;
        float v = (n < 32) ? Ws2[k * 32 + n] : Wn2[k * 32 + (n - 32)];
        short hi = bf16hi(v);
        wt2h[n * 72 + k] = (unsigned short)hi;
        wt2l[n * 72 + k] = (unsigned short)bf16hi(v - bf2f(hi));
    }
}

// ---------------- MFMA dense: [N][64] @ [64][NT*16] ----------
// A layout: A[m=lane&15][k=(lane>>4)*8+j]; C/D: col=lane&15, row=(lane>>4)*4+reg.
// Tiles t<NSELF -> f32 out + bias; t>=NSELF -> bf16 out (neighbor transform).

template<int NT, int NSELF>
__global__ __launch_bounds__(256) void dense_mfma_kernel(
        const float* __restrict__ X,                 // [N][64]
        const unsigned short* __restrict__ wh,       // [NT*16][72] bf16-hi
        const unsigned short* __restrict__ wl,       // [NT*16][72] bf16-lo
        const float* __restrict__ bias,              // [NSELF*16]
        float* __restrict__ outA,                    // row stride sA
        unsigned short* __restrict__ outB,           // row stride sB (bf16 bits)
        int sA, int sB, int N) {
    const int lane = threadIdx.x & 63;
    const int wid  = threadIdx.x >> 6;
    const int m = lane & 15, quad = lane >> 4;
    const int rowblk = blockIdx.x * 128 + wid * 32;

    floatx4 acc[2][NT];
    #pragma unroll
    for (int rt = 0; rt < 2; ++rt)
        #pragma unroll
        for (int t = 0; t < NT; ++t) acc[rt][t] = (floatx4)(0.f);

    short8 ah[2][2], al[2][2];   // [rowset][k-half]
    #pragma unroll
    for (int rt = 0; rt < 2; ++rt) {
        int r = rowblk + rt * 16 + m;
        if (r >= N) r = N - 1;                       // clamped load, store guarded
        const float* xp = X + (size_t)r * 64 + quad * 8;
        #pragma unroll
        for (int h = 0; h < 2; ++h) {
            floatx4 f0 = *(const floatx4*)(xp + h * 32);
            floatx4 f1 = *(const floatx4*)(xp + h * 32 + 4);
            short8 hi, lo;
            #pragma unroll
            for (int j = 0; j < 4; ++j) {
                short hv = bf16hi(f0[j]);
                hi[j] = hv; lo[j] = bf16hi(f0[j] - bf2f(hv));
                short hv2 = bf16hi(f1[j]);
                hi[4 + j] = hv2; lo[4 + j] = bf16hi(f1[j] - bf2f(hv2));
            }
            ah[rt][h] = hi; al[rt][h] = lo;
        }
    }

    #pragma unroll
    for (int t = 0; t < NT; ++t) {
        int n = t * 16 + m;
        const unsigned short* ph = wh + n * 72 + quad * 8;
        const unsigned short* pl = wl + n * 72 + quad * 8;
        #pragma unroll
        for (int h = 0; h < 2; ++h) {
            short8 bh = *(const short8*)(ph + h * 32);
            short8 bl = *(const short8*)(pl + h * 32);
            #pragma unroll
            for (int rt = 0; rt < 2; ++rt) {
                acc[rt][t] = __builtin_amdgcn_mfma_f32_16x16x32_bf16(ah[rt][h], bh, acc[rt][t], 0, 0, 0);
                acc[rt][t] = __builtin_amdgcn_mfma_f32_16x16x32_bf16(al[rt][h], bh, acc[rt][t], 0, 0, 0);
                acc[rt][t] = __builtin_amdgcn_mfma_f32_16x16x32_bf16(ah[rt][h], bl, acc[rt][t], 0, 0, 0);
            }
        }
    }

    #pragma unroll
    for (int rt = 0; rt < 2; ++rt) {
        #pragma unroll
        for (int t = 0; t < NT; ++t) {
            #pragma unroll
            for (int r4 = 0; r4 < 4; ++r4) {
                int row = rowblk + rt * 16 + quad * 4 + r4;
                if (row < N) {
                    if (t < NSELF) {
                        int col = t * 16 + m;
                        outA[(size_t)row * sA + col] = acc[rt][t][r4] + bias[col];
                    } else {
                        int col = (t - NSELF) * 16 + m;
                        outB[(size_t)row * sB + col] = (unsigned short)bf16hi(acc[rt][t][r4]);
                    }
                }
            }
        }
    }
}

// ---------------- fused bucket aggregation ----------------
// One block per 256-node dst bucket. LDS acc stride 66 (index rotation
// (j+c)&7 spreads banks). ds_add_f32 push per edge; epilogue fuses
// mean + self-term + bias-relu.

__global__ __launch_bounds__(512) void agg64_bucket_kernel(
        const unsigned short* __restrict__ t1n,      // [N][64] bf16 bits
        float* __restrict__ xs_io,                   // [N][64] xs -> h1 in place
        const unsigned* __restrict__ region,
        const int* __restrict__ gcursor,
        float* __restrict__ inv_deg, int N) {
    __shared__ float acc[BW2 * 66];                  // 67.6 KB
    const int r = blockIdx.x;
    const int tid = threadIdx.x;
    for (int i = tid; i < BW2 * 66; i += 512) acc[i] = 0.f;
    __syncthreads();
    const int sz = min(gcursor[r], CAP);
    const unsigned* ep = region + (size_t)r * CAP;
    const int g = tid >> 3, c = tid & 7;             // 64 groups x 8 lanes
    for (int i = g; i < sz; i += 64) {
        unsigned e = ep[i];                          // broadcast within group
        int s = (int)(e >> BSH);
        int rel = (int)(e & (BW2 - 1));
        ushort8v u = *(const ushort8v*)(t1n + (size_t)s * 64 + c * 8);
        if (c == 0) atomicAdd(&acc[rel * 66 + 64], 1.0f);
        float* arow = &acc[rel * 66 + c * 8];
        #pragma unroll
        for (int j = 0; j < 8; ++j) {
            int f = (j + c) & 7;                     // rotate: spread banks
            atomicAdd(&arow[f], bits2f(u[f]));
        }
    }
    __syncthreads();
    for (int idx = tid; idx < BW2 * 8; idx += 512) {
        int rel = idx >> 3, cc = idx & 7;
        int node = r * BW2 + rel;
        if (node < N) {
            float inv = 1.0f / fmaxf(acc[rel * 66 + 64], 1.0f);
            if (cc == 0) inv_deg[node] = inv;
            size_t o = (size_t)node * 64 + cc * 8;
            floatx4 x0 = *(const floatx4*)(xs_io + o);
            floatx4 x1 = *(const floatx4*)(xs_io + o + 4);
            floatx4 r0, r1;
            #pragma unroll
            for (int q = 0; q < 4; ++q) {
                r0[q] = fmaxf(x0[q] + acc[rel * 66 + cc * 8 + q] * inv, 0.f);
                r1[q] = fmaxf(x1[q] + acc[rel * 66 + cc * 8 + 4 + q] * inv, 0.f);
            }
            *(floatx4*)(xs_io + o) = r0;
            *(floatx4*)(xs_io + o + 4) = r1;
        }
    }
}

__global__ __launch_bounds__(512) void agg32_bucket_kernel(
        const float* __restrict__ s2,                // [N][32] self + bias
        const unsigned short* __restrict__ t2n,      // [N][32] bf16 bits
        const unsigned* __restrict__ region,
        const int* __restrict__ gcursor,
        const float* __restrict__ inv_deg,
        float* __restrict__ out, int N) {
    __shared__ float acc[BW2 * 34];                  // 34.8 KB
    const int r = blockIdx.x;
    const int tid = threadIdx.x;
    for (int i = tid; i < BW2 * 34; i += 512) acc[i] = 0.f;
    __syncthreads();
    const int sz = min(gcursor[r], CAP);
    const unsigned* ep = region + (size_t)r * CAP;
    const int g = tid >> 2, c = tid & 3;             // 128 groups x 4 lanes
    for (int i = g; i < sz; i += 128) {
        unsigned e = ep[i];
        int s = (int)(e >> BSH);
        int rel = (int)(e & (BW2 - 1));
        ushort8v u = *(const ushort8v*)(t2n + (size_t)s * 32 + c * 8);
        float* arow = &acc[rel * 34 + c * 8];
        #pragma unroll
        for (int j = 0; j < 8; ++j) {
            int f = (j + 2 * c) & 7;
            atomicAdd(&arow[f], bits2f(u[f]));
        }
    }
    __syncthreads();
    for (int idx = tid; idx < BW2 * 4; idx += 512) {
        int rel = idx >> 2, cc = idx & 3;
        int node = r * BW2 + rel;
        if (node < N) {
            float inv = inv_deg[node];
            size_t o = (size_t)node * 32 + cc * 8;
            floatx4 a0 = *(const floatx4*)(s2 + o);
            floatx4 a1 = *(const floatx4*)(s2 + o + 4);
            floatx4 r0, r1;
            #pragma unroll
            for (int q = 0; q < 4; ++q) {
                r0[q] = a0[q] + acc[rel * 34 + cc * 8 + q] * inv;
                r1[q] = a1[q] + acc[rel * 34 + cc * 8 + 4 + q] * inv;
            }
            *(floatx4*)(out + o) = r0;
            *(floatx4*)(out + o + 4) = r1;
        }
    }
}

// ---------------- fallback (round-2 atomic path) ----------------

__global__ __launch_bounds__(256) void deg_kernel(const int* __restrict__ dst,
                                                  float* __restrict__ deg, int E) {
    int e = blockIdx.x * blockDim.x + threadIdx.x;
    if (e < E) atomicAdd(&deg[dst[e]], 1.0f);
}

__global__ __launch_bounds__(256) void agg_atomic_kernel(const float* __restrict__ feats,
                                                         const int* __restrict__ src,
                                                         const int* __restrict__ dst,
                                                         float* __restrict__ agg, int E) {
    int tid = blockIdx.x * blockDim.x + threadIdx.x;
    if (tid >= E * NF) return;
    int e = tid >> 6, f = tid & 63;
    atomicAdd(&agg[(size_t)dst[e] * NF + f], feats[(size_t)src[e] * NF + f]);
}

__global__ __launch_bounds__(256) void layer1_fb_kernel(const float* __restrict__ x,
                                                        const float* __restrict__ agg,
                                                        const float* __restrict__ deg,
                                                        const float* __restrict__ Wself,
                                                        const float* __restrict__ Wneigh,
                                                        const float* __restrict__ b,
                                                        float* __restrict__ h1, int N) {
    int tid = blockIdx.x * blockDim.x + threadIdx.x;
    if (tid >= N * NF) return;
    int n = tid >> 6, c = tid & 63;
    float inv = 1.0f / fmaxf(deg[n], 1.0f);
    const float* xrow = x + (size_t)n * NF;
    const float* arow = agg + (size_t)n * NF;
    float acc = b[c];
    #pragma unroll
    for (int k = 0; k < NF; ++k) {
        acc += xrow[k] * Wself[k * NF + c];
        acc += (arow[k] * inv) * Wneigh[k * NF + c];
    }
    h1[tid] = fmaxf(acc, 0.f);
}

__global__ __launch_bounds__(256) void layer2_fb_kernel(const float* __restrict__ h1,
                                                        const float* __restrict__ agg,
                                                        const float* __restrict__ deg,
                                                        const float* __restrict__ Wself,
                                                        const float* __restrict__ Wneigh,
                                                        const float* __restrict__ b,
                                                        float* __restrict__ out, int N) {
    int tid = blockIdx.x * blockDim.x + threadIdx.x;
    if (tid >= N * 32) return;
    int n = tid >> 5, c = tid & 31;
    float inv = 1.0f / fmaxf(deg[n], 1.0f);
    const float* hrow = h1 + (size_t)n * NF;
    const float* arow = agg + (size_t)n * NF;
    float acc = b[c];
    #pragma unroll
    for (int k = 0; k < NF; ++k) {
        acc += hrow[k] * Wself[k * 32 + c];
        acc += (arow[k] * inv) * Wneigh[k * 32 + c];
    }
    out[tid] = acc;
}

// ---------------- launch ----------------

extern "C" void kernel_launch(void* const* d_in, const int* in_sizes, int n_in,
                              void* d_out, int out_size, void* d_ws, size_t ws_size,
                              hipStream_t stream) {
    const float* x        = (const float*)d_in[0];
    const int*   src      = (const int*)d_in[1];
    const int*   dst      = (const int*)d_in[2];
    const float* W_self1  = (const float*)d_in[3];
    const float* W_neigh1 = (const float*)d_in[4];
    const float* b1       = (const float*)d_in[5];
    const float* W_self2  = (const float*)d_in[6];
    const float* W_neigh2 = (const float*)d_in[7];
    const float* b2       = (const float*)d_in[8];
    float* out = (float*)d_out;

    const int N = in_sizes[0] / NF;            // 100000
    const int E = in_sizes[1];                 // 1250000
    const int nb2 = (N + BW2 - 1) / BW2;       // 391

    // ws layout; every segment 16B-aligned
    int*   gcursor  = (int*)d_ws;                              // [MAXB]
    float* inv_deg  = (float*)(gcursor + MAXB);                // [N]
    unsigned* region = (unsigned*)(inv_deg + (((size_t)N + 7) & ~7ull));  // [nb2*CAP]
    unsigned short* wt1h = (unsigned short*)(region + (size_t)nb2 * CAP);
    unsigned short* wt1l = wt1h + 128 * 72;
    unsigned short* wt2h = wt1l + 128 * 72;
    unsigned short* wt2l = wt2h + 64 * 72;
    float* bufA = (float*)(wt2l + 64 * 72);                    // xs -> h1 (f32)
    // region B (aliased): t1n bf16 [N][64] (layer1), then s2 f32 [N][32] + t2n bf16 [N][32]
    char* regB = (char*)(bufA + (size_t)N * NF);
    unsigned short* t1n = (unsigned short*)regB;
    float*          s2  = (float*)regB;
    unsigned short* t2n = (unsigned short*)(regB + (size_t)N * 32 * sizeof(float));
    size_t regBsz = (size_t)N * 32 * sizeof(float) + (size_t)N * 32 * sizeof(unsigned short);
    if ((size_t)N * 64 * sizeof(unsigned short) > regBsz) regBsz = (size_t)N * 64 * sizeof(unsigned short);
    size_t need = (size_t)(regB - (char*)d_ws) + regBsz;       // ~54.9 MB

    bool fast = ws_size >= need
             && nb2 <= MAXB
             && (size_t)E * 3 / (2 * (size_t)nb2) <= CAP       // 1.5x headroom over mean
             && N < (1 << 24);                                 // src fits in 24 bits

    if (fast) {
        hipMemsetAsync(gcursor, 0, MAXB * sizeof(int), stream);
        p1_bucket_kernel<<<(E + P1_CHUNK - 1) / P1_CHUNK, 256, 0, stream>>>(
            src, dst, gcursor, region, E, nb2);
        wprep_kernel<<<(128 * 64 + 64 * 64 + 255) / 256, 256, 0, stream>>>(
            W_self1, W_neigh1, W_self2, W_neigh2, wt1h, wt1l, wt2h, wt2l);

        int dblocks = (N + 127) / 128;
        // layer 1
        dense_mfma_kernel<8, 4><<<dblocks, 256, 0, stream>>>(x, wt1h, wt1l, b1,
                                                             bufA, t1n, 64, 64, N);
        agg64_bucket_kernel<<<nb2, 512, 0, stream>>>(t1n, bufA, region, gcursor,
                                                     inv_deg, N);
        // layer 2
        dense_mfma_kernel<4, 2><<<dblocks, 256, 0, stream>>>(bufA, wt2h, wt2l, b2,
                                                             s2, t2n, 32, 32, N);
        agg32_bucket_kernel<<<nb2, 512, 0, stream>>>(s2, t2n, region, gcursor,
                                                     inv_deg, out, N);
    } else {
        // fallback: atomic path (~51.6 MB)
        float* deg = (float*)d_ws;
        float* agg = deg + N;
        float* h1  = agg + (size_t)N * NF;
        hipMemsetAsync(deg, 0, (size_t)(N + (size_t)N * NF) * sizeof(float), stream);
        deg_kernel<<<(E + 255) / 256, 256, 0, stream>>>(dst, deg, E);
        int at = E * NF;
        agg_atomic_kernel<<<(at + 255) / 256, 256, 0, stream>>>(x, src, dst, agg, E);
        layer1_fb_kernel<<<(N * NF + 255) / 256, 256, 0, stream>>>(x, agg, deg, W_self1,
                                                                   W_neigh1, b1, h1, N);
        hipMemsetAsync(agg, 0, (size_t)N * NF * sizeof(float), stream);
        agg_atomic_kernel<<<(at + 255) / 256, 256, 0, stream>>>(h1, src, dst, agg, E);
        layer2_fb_kernel<<<(N * 32 + 255) / 256, 256, 0, stream>>>(h1, agg, deg, W_self2,
                                                                   W_neigh2, b2, out, N);
    }
}

// Round 8
// 242.828 us; speedup vs baseline: 3.9628x; 3.9628x over previous
//
#include <hip/hip_runtime.h>
#include <hip/hip_bf16.h>

// GraphSAGE 2-layer forward. N=100000, E=1250000, 64 -> 64 -> 32, fp32.
//
// Round-8: revert to round-6 structure (two-phase counting-sort CSR + MFMA
// dense + wave-per-node gather agg; 256.6 us proven). Round-7 lesson: bucket-
// resident LDS accumulation starves the chip (391 blocks, 1 blk/CU, serialized
// LDS atomics) - keep O(N) waves. This round cuts graph nodes 10 -> 7:
//   zerok  : zero gcursor (1 block)
//   p1     : bucket edges by dst>>9 into per-bucket regions, (src<<9)|rel
//   p2     : per-bucket base (inline prefix over gcursor) + LDS count/scan
//            -> row_start segment + csr scatter (exclusive window per block)
//   dense1 : bufA = x@Ws1+b1 (f32), t1n = bf16(x@Wn1)  (MFMA split-bf16,
//            weights split+transposed into LDS in-kernel; wprep deleted)
//   agg64  : bufA = relu(bufA + mean t1n[src])  (ILP-2 gather)
//   dense2 : s2 = h1@Ws2+b2 (f32), t2n = bf16(h1@Wn2)
//   agg32  : out = s2 + mean t2n[src]           (ILP-2 gather)

#define NF 64
#define BW 512            // bucket width (nodes); rel = dst & 511
#define BSH 9
#define MAXB 512          // max buckets (LDS arrays)
#define CAPMAX 16384      // max edges per bucket region (mean 6378)
#define P1_CHUNK 4096

typedef __attribute__((ext_vector_type(8))) short short8;
typedef __attribute__((ext_vector_type(8))) unsigned short ushort8v;
typedef __attribute__((ext_vector_type(4))) float floatx4;

__device__ __forceinline__ short bf16hi(float v) {
    __hip_bfloat16 h = __float2bfloat16(v);
    return *(short*)&h;
}
__device__ __forceinline__ float bf2f(short s) {
    __hip_bfloat16 h = *(__hip_bfloat16*)&s;
    return __bfloat162float(h);
}
__device__ __forceinline__ float bits2f(unsigned short u) {
    unsigned int x = ((unsigned int)u) << 16;
    union { unsigned int i; float f; } c; c.i = x; return c.f;
}

// ---------------- zero ----------------

__global__ __launch_bounds__(512) void zero_kernel(int* __restrict__ g) {
    if (threadIdx.x < MAXB) g[threadIdx.x] = 0;
}

// ---------------- CSR build: counting sort ----------------

// p1: bucket the edge list. grid = ceil(E / P1_CHUNK)
__global__ __launch_bounds__(256) void p1_bucket_kernel(const int* __restrict__ src,
                                                        const int* __restrict__ dst,
                                                        int* __restrict__ gcursor,
                                                        unsigned* __restrict__ bucket,
                                                        int E, int nbuckets) {
    __shared__ int cnt[MAXB];
    __shared__ int cbase[MAXB];
    const int beg = blockIdx.x * P1_CHUNK;
    const int end = min(E, beg + P1_CHUNK);
    for (int i = threadIdx.x; i < nbuckets; i += 256) cnt[i] = 0;
    __syncthreads();
    for (int e = beg + threadIdx.x; e < end; e += 256)
        atomicAdd(&cnt[dst[e] >> BSH], 1);
    __syncthreads();
    for (int i = threadIdx.x; i < nbuckets; i += 256) {
        int c = cnt[i];
        cbase[i] = c ? atomicAdd(&gcursor[i], c) : 0;
        cnt[i] = 0;                              // reuse as local cursor
    }
    __syncthreads();
    for (int e = beg + threadIdx.x; e < end; e += 256) {
        int d = dst[e];
        int r = d >> BSH;
        int p = cbase[r] + atomicAdd(&cnt[r], 1);
        if (p < CAPMAX)                          // clamp: no OOB even if skewed
            bucket[(size_t)r * CAPMAX + p] = ((unsigned)src[e] << BSH) | (unsigned)(d & (BW - 1));
    }
}

// p2: one block per bucket. Inline base = prefix of gcursor; then LDS
// count+scan; row_start segment + csr scatter in exclusive window.
__global__ __launch_bounds__(256) void p2_csr_kernel(const unsigned* __restrict__ bucket,
                                                     const int* __restrict__ gcursor,
                                                     int* __restrict__ row_start,
                                                     int* __restrict__ csr_src,
                                                     int N, int nbuckets) {
    __shared__ unsigned stage[CAPMAX];   // 64 KB
    __shared__ int cnt[BW];
    __shared__ int excl[BW];
    const int r = blockIdx.x;
    const int tid = threadIdx.x;

    // base = sum_{i<r} min(gcursor[i], CAPMAX)   (excl[] as scratch)
    int partial = 0;
    for (int i = tid; i < r; i += 256) partial += min(gcursor[i], CAPMAX);
    excl[tid] = partial;
    __syncthreads();
    for (int off = 128; off > 0; off >>= 1) {
        if (tid < off) excl[tid] += excl[tid + off];
        __syncthreads();
    }
    const int base = excl[0];
    const int sz = min(gcursor[r], CAPMAX);
    const unsigned* bsrc = bucket + (size_t)r * CAPMAX;
    __syncthreads();

    for (int i = tid; i < BW; i += 256) cnt[i] = 0;
    __syncthreads();
    for (int i = tid; i < sz; i += 256) {
        unsigned v = bsrc[i];
        stage[i] = v;
        atomicAdd(&cnt[v & (BW - 1)], 1);
    }
    __syncthreads();
    // inclusive scan of cnt into excl (Hillis-Steele, 2 elems/thread)
    excl[tid] = cnt[tid];
    excl[tid + 256] = cnt[tid + 256];
    __syncthreads();
    for (int off = 1; off < BW; off <<= 1) {
        int v0 = (tid >= off) ? excl[tid - off] : 0;
        int i1 = tid + 256;
        int v1 = (i1 >= off) ? excl[i1 - off] : 0;
        __syncthreads();
        excl[tid] += v0;
        excl[i1] += v1;
        __syncthreads();
    }
    // row_start segment (exclusive = inclusive - count)
    for (int i = tid; i < BW; i += 256) {
        int node = r * BW + i;
        if (node < N) row_start[node] = base + excl[i] - cnt[i];
    }
    if (r == nbuckets - 1 && tid == 0) row_start[N] = base + sz;
    __syncthreads();
    for (int i = tid; i < BW; i += 256) cnt[i] = excl[i] - cnt[i];  // cursors
    __syncthreads();
    for (int i = tid; i < sz; i += 256) {
        unsigned v = stage[i];
        int p = atomicAdd(&cnt[v & (BW - 1)], 1);
        csr_src[base + p] = (int)(v >> BSH);     // window owned by this block only
    }
}

// ---------------- MFMA dense: [N][64] @ [64][NT*16] ----------
// A layout: A[m=lane&15][k=(lane>>4)*8+j]; C/D: col=lane&15, row=(lane>>4)*4+reg.
// Weights split+transposed to bf16 hi/lo in LDS ([n][72] pad, 2-way banks = free).
// Tiles t<NSELF -> f32 out + bias; t>=NSELF -> bf16 out (neighbor transform).

template<int NT, int NSELF>
__global__ __launch_bounds__(256) void dense_mfma_kernel(
        const float* __restrict__ X,                 // [N][64]
        const float* __restrict__ Wself,             // [64][HALF] k-major
        const float* __restrict__ Wneigh,            // [64][HALF] k-major
        const float* __restrict__ bias,              // [NSELF*16]
        float* __restrict__ outA,                    // row stride sA
        unsigned short* __restrict__ outB,           // row stride sB (bf16 bits)
        int sA, int sB, int N) {
    constexpr int NO = NT * 16;                      // out cols total (128 / 64)
    constexpr int HALF = NO / 2;
    __shared__ unsigned short wh[NO * 72];
    __shared__ unsigned short wl[NO * 72];
    const int tid = threadIdx.x;
    for (int i = tid; i < NO * 64; i += 256) {
        int n = i & (NO - 1), k = i / NO;            // consecutive tid -> coalesced
        float v = (n < HALF) ? Wself[k * HALF + n] : Wneigh[k * HALF + (n - HALF)];
        short hv = bf16hi(v);
        wh[n * 72 + k] = (unsigned short)hv;
        wl[n * 72 + k] = (unsigned short)bf16hi(v - bf2f(hv));
    }

    const int lane = tid & 63;
    const int wid  = tid >> 6;
    const int m = lane & 15, quad = lane >> 4;
    const int rowblk = blockIdx.x * 128 + wid * 32;

    floatx4 acc[2][NT];
    #pragma unroll
    for (int rt = 0; rt < 2; ++rt)
        #pragma unroll
        for (int t = 0; t < NT; ++t) acc[rt][t] = (floatx4)(0.f);

    short8 ah[2][2], al[2][2];   // [rowset][k-half]
    #pragma unroll
    for (int rt = 0; rt < 2; ++rt) {
        int r = rowblk + rt * 16 + m;
        if (r >= N) r = N - 1;                       // clamped load, store guarded
        const float* xp = X + (size_t)r * 64 + quad * 8;
        #pragma unroll
        for (int h = 0; h < 2; ++h) {
            floatx4 f0 = *(const floatx4*)(xp + h * 32);
            floatx4 f1 = *(const floatx4*)(xp + h * 32 + 4);
            short8 hi, lo;
            #pragma unroll
            for (int j = 0; j < 4; ++j) {
                short hv = bf16hi(f0[j]);
                hi[j] = hv; lo[j] = bf16hi(f0[j] - bf2f(hv));
                short hv2 = bf16hi(f1[j]);
                hi[4 + j] = hv2; lo[4 + j] = bf16hi(f1[j] - bf2f(hv2));
            }
            ah[rt][h] = hi; al[rt][h] = lo;
        }
    }
    __syncthreads();                                 // weights staged

    #pragma unroll
    for (int t = 0; t < NT; ++t) {
        int n = t * 16 + m;
        const unsigned short* ph = wh + n * 72 + quad * 8;
        const unsigned short* pl = wl + n * 72 + quad * 8;
        #pragma unroll
        for (int h = 0; h < 2; ++h) {
            short8 bh = *(const short8*)(ph + h * 32);
            short8 bl = *(const short8*)(pl + h * 32);
            #pragma unroll
            for (int rt = 0; rt < 2; ++rt) {
                acc[rt][t] = __builtin_amdgcn_mfma_f32_16x16x32_bf16(ah[rt][h], bh, acc[rt][t], 0, 0, 0);
                acc[rt][t] = __builtin_amdgcn_mfma_f32_16x16x32_bf16(al[rt][h], bh, acc[rt][t], 0, 0, 0);
                acc[rt][t] = __builtin_amdgcn_mfma_f32_16x16x32_bf16(ah[rt][h], bl, acc[rt][t], 0, 0, 0);
            }
        }
    }

    #pragma unroll
    for (int rt = 0; rt < 2; ++rt) {
        #pragma unroll
        for (int t = 0; t < NT; ++t) {
            #pragma unroll
            for (int r4 = 0; r4 < 4; ++r4) {
                int row = rowblk + rt * 16 + quad * 4 + r4;
                if (row < N) {
                    if (t < NSELF) {
                        int col = t * 16 + m;
                        outA[(size_t)row * sA + col] = acc[rt][t][r4] + bias[col];
                    } else {
                        int col = (t - NSELF) * 16 + m;
                        outB[(size_t)row * sB + col] = (unsigned short)bf16hi(acc[rt][t][r4]);
                    }
                }
            }
        }
    }
}

// ---------------- CSR aggregation (bf16 gathers, wide waves, ILP-2) ----------

// bufA[n] = relu(bufA[n] + mean_s t1n[s]); 8 groups of 8 lanes, 16 rows in flight
__global__ __launch_bounds__(256) void agg64_kernel(const unsigned short* __restrict__ t1n,
                                                    float* __restrict__ xs_io,
                                                    const int* __restrict__ row_start,
                                                    const int* __restrict__ csr_src, int N) {
    int n = (blockIdx.x * blockDim.x + threadIdx.x) >> 6;
    if (n >= N) return;
    int lane = threadIdx.x & 63;
    int g = lane >> 3, c = lane & 7;                 // lane covers feats c*8..c*8+7
    int beg = row_start[n], end = row_start[n + 1];
    float acc[8] = {0.f, 0.f, 0.f, 0.f, 0.f, 0.f, 0.f, 0.f};
    for (int j = beg + g; j < end; j += 16) {
        int j2 = j + 8;
        int s0 = csr_src[j];
        ushort8v u0 = *(const ushort8v*)(t1n + (size_t)s0 * 64 + c * 8);
        if (j2 < end) {
            int s1 = csr_src[j2];
            ushort8v u1 = *(const ushort8v*)(t1n + (size_t)s1 * 64 + c * 8);
            #pragma unroll
            for (int i = 0; i < 8; ++i) acc[i] += bits2f(u0[i]) + bits2f(u1[i]);
        } else {
            #pragma unroll
            for (int i = 0; i < 8; ++i) acc[i] += bits2f(u0[i]);
        }
    }
    #pragma unroll
    for (int i = 0; i < 8; ++i) {
        float v = acc[i];
        v += __shfl_xor(v, 8);
        v += __shfl_xor(v, 16);
        v += __shfl_xor(v, 32);
        acc[i] = v;
    }
    if (g == 0) {
        float inv = 1.0f / fmaxf((float)(end - beg), 1.0f);
        size_t o = (size_t)n * 64 + c * 8;
        floatx4 x0 = *(const floatx4*)(xs_io + o);
        floatx4 x1 = *(const floatx4*)(xs_io + o + 4);
        floatx4 r0, r1;
        #pragma unroll
        for (int i = 0; i < 4; ++i) {
            r0[i] = fmaxf(x0[i] + acc[i] * inv, 0.f);
            r1[i] = fmaxf(x1[i] + acc[4 + i] * inv, 0.f);
        }
        *(floatx4*)(xs_io + o) = r0;
        *(floatx4*)(xs_io + o + 4) = r1;
    }
}

// out[n] = s2[n] + mean_s t2n[s]; 16 groups of 4 lanes, 32 rows in flight
__global__ __launch_bounds__(256) void agg32_kernel(const float* __restrict__ s2,
                                                    const unsigned short* __restrict__ t2n,
                                                    const int* __restrict__ row_start,
                                                    const int* __restrict__ csr_src,
                                                    float* __restrict__ out, int N) {
    int n = (blockIdx.x * blockDim.x + threadIdx.x) >> 6;
    if (n >= N) return;
    int lane = threadIdx.x & 63;
    int g = lane >> 2, c = lane & 3;                 // lane covers feats c*8..c*8+7
    int beg = row_start[n], end = row_start[n + 1];
    float acc[8] = {0.f, 0.f, 0.f, 0.f, 0.f, 0.f, 0.f, 0.f};
    for (int j = beg + g; j < end; j += 32) {
        int j2 = j + 16;
        int s0 = csr_src[j];
        ushort8v u0 = *(const ushort8v*)(t2n + (size_t)s0 * 32 + c * 8);
        if (j2 < end) {
            int s1 = csr_src[j2];
            ushort8v u1 = *(const ushort8v*)(t2n + (size_t)s1 * 32 + c * 8);
            #pragma unroll
            for (int i = 0; i < 8; ++i) acc[i] += bits2f(u0[i]) + bits2f(u1[i]);
        } else {
            #pragma unroll
            for (int i = 0; i < 8; ++i) acc[i] += bits2f(u0[i]);
        }
    }
    #pragma unroll
    for (int i = 0; i < 8; ++i) {
        float v = acc[i];
        v += __shfl_xor(v, 4);
        v += __shfl_xor(v, 8);
        v += __shfl_xor(v, 16);
        v += __shfl_xor(v, 32);
        acc[i] = v;
    }
    if (g == 0) {
        float inv = 1.0f / fmaxf((float)(end - beg), 1.0f);
        size_t o = (size_t)n * 32 + c * 8;
        floatx4 s0 = *(const floatx4*)(s2 + o);
        floatx4 s1 = *(const floatx4*)(s2 + o + 4);
        floatx4 r0, r1;
        #pragma unroll
        for (int i = 0; i < 4; ++i) {
            r0[i] = s0[i] + acc[i] * inv;
            r1[i] = s1[i] + acc[4 + i] * inv;
        }
        *(floatx4*)(out + o) = r0;
        *(floatx4*)(out + o + 4) = r1;
    }
}

// ---------------- fallback (round-2 atomic path) ----------------

__global__ __launch_bounds__(256) void deg_kernel(const int* __restrict__ dst,
                                                  float* __restrict__ deg, int E) {
    int e = blockIdx.x * blockDim.x + threadIdx.x;
    if (e < E) atomicAdd(&deg[dst[e]], 1.0f);
}

__global__ __launch_bounds__(256) void agg_atomic_kernel(const float* __restrict__ feats,
                                                         const int* __restrict__ src,
                                                         const int* __restrict__ dst,
                                                         float* __restrict__ agg, int E) {
    int tid = blockIdx.x * blockDim.x + threadIdx.x;
    if (tid >= E * NF) return;
    int e = tid >> 6, f = tid & 63;
    atomicAdd(&agg[(size_t)dst[e] * NF + f], feats[(size_t)src[e] * NF + f]);
}

__global__ __launch_bounds__(256) void layer1_fb_kernel(const float* __restrict__ x,
                                                        const float* __restrict__ agg,
                                                        const float* __restrict__ deg,
                                                        const float* __restrict__ Wself,
                                                        const float* __restrict__ Wneigh,
                                                        const float* __restrict__ b,
                                                        float* __restrict__ h1, int N) {
    int tid = blockIdx.x * blockDim.x + threadIdx.x;
    if (tid >= N * NF) return;
    int n = tid >> 6, c = tid & 63;
    float inv = 1.0f / fmaxf(deg[n], 1.0f);
    const float* xrow = x + (size_t)n * NF;
    const float* arow = agg + (size_t)n * NF;
    float acc = b[c];
    #pragma unroll
    for (int k = 0; k < NF; ++k) {
        acc += xrow[k] * Wself[k * NF + c];
        acc += (arow[k] * inv) * Wneigh[k * NF + c];
    }
    h1[tid] = fmaxf(acc, 0.f);
}

__global__ __launch_bounds__(256) void layer2_fb_kernel(const float* __restrict__ h1,
                                                        const float* __restrict__ agg,
                                                        const float* __restrict__ deg,
                                                        const float* __restrict__ Wself,
                                                        const float* __restrict__ Wneigh,
                                                        const float* __restrict__ b,
                                                        float* __restrict__ out, int N) {
    int tid = blockIdx.x * blockDim.x + threadIdx.x;
    if (tid >= N * 32) return;
    int n = tid >> 5, c = tid & 31;
    float inv = 1.0f / fmaxf(deg[n], 1.0f);
    const float* hrow = h1 + (size_t)n * NF;
    const float* arow = agg + (size_t)n * NF;
    float acc = b[c];
    #pragma unroll
    for (int k = 0; k < NF; ++k) {
        acc += hrow[k] * Wself[k * 32 + c];
        acc += (arow[k] * inv) * Wneigh[k * 32 + c];
    }
    out[tid] = acc;
}

// ---------------- launch ----------------

extern "C" void kernel_launch(void* const* d_in, const int* in_sizes, int n_in,
                              void* d_out, int out_size, void* d_ws, size_t ws_size,
                              hipStream_t stream) {
    const float* x        = (const float*)d_in[0];
    const int*   src      = (const int*)d_in[1];
    const int*   dst      = (const int*)d_in[2];
    const float* W_self1  = (const float*)d_in[3];
    const float* W_neigh1 = (const float*)d_in[4];
    const float* b1       = (const float*)d_in[5];
    const float* W_self2  = (const float*)d_in[6];
    const float* W_neigh2 = (const float*)d_in[7];
    const float* b2       = (const float*)d_in[8];
    float* out = (float*)d_out;

    const int N = in_sizes[0] / NF;          // 100000
    const int E = in_sizes[1];               // 1250000
    const int nbuckets = (N + BW - 1) / BW;  // 196

    // ws layout; every segment 16B-aligned
    const size_t rsPad = ((size_t)N + 8) & ~7ull;
    int* gcursor   = (int*)d_ws;                      // [MAXB]
    int* row_start = gcursor + MAXB;                  // [N+1] padded
    int* csr_src   = row_start + rsPad;               // [E]
    float* bufA = (float*)(csr_src + (((size_t)E + 7) & ~7ull));  // xs -> h1 (f32)
    unsigned* bucket = (unsigned*)bufA;               // [nbuckets][CAPMAX], dead before dense1
    // region B (aliased): t1n bf16 [N][64] (layer1), then s2 f32 [N][32] + t2n bf16 [N][32]
    char* regB = (char*)(bufA + (size_t)N * NF);
    unsigned short* t1n = (unsigned short*)regB;
    float*          s2  = (float*)regB;
    unsigned short* t2n = (unsigned short*)(regB + (size_t)N * 32 * sizeof(float));
    size_t regBsz = (size_t)N * 32 * sizeof(float) + (size_t)N * 32 * sizeof(unsigned short);
    if ((size_t)N * 64 * sizeof(unsigned short) > regBsz) regBsz = (size_t)N * 64 * sizeof(unsigned short);
    size_t need = (size_t)(regB - (char*)d_ws) + regBsz;   // ~50.2 MB

    bool fast = ws_size >= need
             && nbuckets <= MAXB
             && (size_t)nbuckets * CAPMAX <= (size_t)N * NF      // bucket fits in bufA alias
             && (size_t)E * 2 / (size_t)nbuckets <= CAPMAX       // 2x headroom over mean
             && N < (1 << 23);                                   // src fits in 23 bits

    if (fast) {
        zero_kernel<<<1, 512, 0, stream>>>(gcursor);
        p1_bucket_kernel<<<(E + P1_CHUNK - 1) / P1_CHUNK, 256, 0, stream>>>(
            src, dst, gcursor, bucket, E, nbuckets);
        p2_csr_kernel<<<nbuckets, 256, 0, stream>>>(bucket, gcursor,
                                                    row_start, csr_src, N, nbuckets);
        int dblocks = (N + 127) / 128;
        // layer 1
        dense_mfma_kernel<8, 4><<<dblocks, 256, 0, stream>>>(x, W_self1, W_neigh1, b1,
                                                             bufA, t1n, 64, 64, N);
        agg64_kernel<<<(N * 64 + 255) / 256, 256, 0, stream>>>(t1n, bufA,
                                                               row_start, csr_src, N);
        // layer 2
        dense_mfma_kernel<4, 2><<<dblocks, 256, 0, stream>>>(bufA, W_self2, W_neigh2, b2,
                                                             s2, t2n, 32, 32, N);
        agg32_kernel<<<(N * 64 + 255) / 256, 256, 0, stream>>>(s2, t2n, row_start,
                                                               csr_src, out, N);
    } else {
        // fallback: atomic path (~51.6 MB)
        float* deg = (float*)d_ws;
        float* agg = deg + N;
        float* h1  = agg + (size_t)N * NF;
        hipMemsetAsync(deg, 0, (size_t)(N + (size_t)N * NF) * sizeof(float), stream);
        deg_kernel<<<(E + 255) / 256, 256, 0, stream>>>(dst, deg, E);
        int at = E * NF;
        agg_atomic_kernel<<<(at + 255) / 256, 256, 0, stream>>>(x, src, dst, agg, E);
        layer1_fb_kernel<<<(N * NF + 255) / 256, 256, 0, stream>>>(x, agg, deg, W_self1,
                                                                   W_neigh1, b1, h1, N);
        hipMemsetAsync(agg, 0, (size_t)N * NF * sizeof(float), stream);
        agg_atomic_kernel<<<(at + 255) / 256, 256, 0, stream>>>(h1, src, dst, agg, E);
        layer2_fb_kernel<<<(N * 32 + 255) / 256, 256, 0, stream>>>(h1, agg, deg, W_self2,
                                                                   W_neigh2, b2, out, N);
    }
}